// Round 13
// baseline (612.275 us; speedup 1.0000x reference)
//
#include <hip/hip_runtime.h>
#include <hip/hip_bf16.h>
#include <math.h>

#define BB 8
#define LL 2048
#define LH 1024            // half sequence (recurrence runs in two passes)
#define DD 128

// ---------------------------------------------------------------------------
// DPP helpers: full-rate VALU cross-lane adds (no LDS in the serial chain).
// ---------------------------------------------------------------------------
template <int CTRL>
__device__ __forceinline__ float dpp_add(float x) {
    int xi = __float_as_int(x);
    int yi = __builtin_amdgcn_update_dpp(xi, xi, CTRL, 0xF, 0xF, false);
    return x + __int_as_float(yi);
}
// 16-lane allreduce: ^1, ^2 (quad_perm), ^:8 (half_mirror), ^:16 (mirror)
__device__ __forceinline__ float allreduce16(float p) {
    p = dpp_add<0xB1>(p);
    p = dpp_add<0x4E>(p);
    p = dpp_add<0x141>(p);
    p = dpp_add<0x140>(p);
    return p;
}
__device__ __forceinline__ float rlane(float p, int l) {
    return __int_as_float(__builtin_amdgcn_readlane(__float_as_int(p), l));
}

// ---------------------------------------------------------------------------
// C[M,O] = X @ W[O,128]^T, optional sigmoid. X rows addressed with (batch,
// half) strides: row m -> b=m>>11, t=m&2047, h=t>>10, tl=t&1023;
// addr = X + b*sB + h*sH + tl*ldx.   (proven R11)
// ---------------------------------------------------------------------------
__global__ __launch_bounds__(256) void gemm_kernel(
    const float* __restrict__ X, long ldx, long sB, long sH,
    const float* __restrict__ W,
    float* __restrict__ C, int ldc,
    int applySig)
{
    __shared__ float Xs[32 * 132];
    __shared__ float Ws[64 * 132];
    const int tid = threadIdx.x;
    const int m0 = blockIdx.x * 32;
    const int o0 = blockIdx.y * 64;
    {
        int row = tid >> 3, cg = tid & 7;
        int m = m0 + row;
        int b = m >> 11, t = m & 2047, h = t >> 10, tl = t & 1023;
        const float* src = X + (size_t)b * sB + (size_t)h * sH
                             + (size_t)tl * ldx + cg * 16;
        float* dst = Xs + row * 132 + cg * 16;
#pragma unroll
        for (int u = 0; u < 4; ++u)
            *(float4*)(dst + 4 * u) = *(const float4*)(src + 4 * u);
    }
    {
        int o = tid >> 2, cg = tid & 3;
        const float* src = W + (size_t)(o0 + o) * 128 + cg * 32;
        float* dst = Ws + o * 132 + cg * 32;
#pragma unroll
        for (int u = 0; u < 8; ++u)
            *(float4*)(dst + 4 * u) = *(const float4*)(src + 4 * u);
    }
    __syncthreads();
    const int tx = tid & 31, ty = tid >> 5;
    float acc[4][2] = {};
    const float* xb = Xs + (ty * 4) * 132;
    const float* wb = Ws + (tx * 2) * 132;
    for (int k0 = 0; k0 < 128; k0 += 4) {
        float4 xr[4], wr[2];
#pragma unroll
        for (int r = 0; r < 4; ++r) xr[r] = *(const float4*)(xb + r * 132 + k0);
#pragma unroll
        for (int cc = 0; cc < 2; ++cc) wr[cc] = *(const float4*)(wb + cc * 132 + k0);
#pragma unroll
        for (int r = 0; r < 4; ++r)
#pragma unroll
            for (int cc = 0; cc < 2; ++cc) {
                acc[r][cc] += xr[r].x * wr[cc].x + xr[r].y * wr[cc].y
                            + xr[r].z * wr[cc].z + xr[r].w * wr[cc].w;
            }
    }
#pragma unroll
    for (int r = 0; r < 4; ++r)
#pragma unroll
        for (int cc = 0; cc < 2; ++cc) {
            float v = acc[r][cc];
            if (applySig) v = 1.0f / (1.0f + __expf(-v));
            C[(size_t)(m0 + ty * 4 + r) * ldc + o0 + tx * 2 + cc] = v;
        }
}

// ---------------------------------------------------------------------------
// Depthwise conv(K=3) + sigmoid + L2-norm for q,k; packs the recurrence
// stream TIME-BLOCKED (TB=4): for batch b, block tb=t>>2, ti=t&3:
//   pack2[(b*512 + tb)*2560 + (o*128 + d)*4 + ti],  o in {k,m,a,q,v}
// ---------------------------------------------------------------------------
__global__ __launch_bounds__(256) void convnorm_kernel(
    const float* __restrict__ qkv,
    const float* __restrict__ qw, const float* __restrict__ qb,
    const float* __restrict__ kw, const float* __restrict__ kb,
    const float* __restrict__ ab,
    float* __restrict__ pack)
{
    const int tid = threadIdx.x;
    const int lane = tid & 63;
    const int wid = tid >> 6;
    const int m = blockIdx.x * 4 + wid;     // b*L + l
    const int l = m & (LL - 1);
    const int b = m >> 11;
    const int d0 = lane * 2;
    float yq0 = qb[d0], yq1 = qb[d0 + 1];
    float yk0 = kb[d0], yk1 = kb[d0 + 1];
#pragma unroll
    for (int tau = 0; tau < 3; ++tau) {
        int lp = l + tau - 1;
        if (lp >= 0 && lp < LL) {
            const float* base = qkv + (size_t)(m + tau - 1) * 512;
            yq0 += base[d0]       * qw[d0 * 3 + tau];
            yq1 += base[d0 + 1]   * qw[(d0 + 1) * 3 + tau];
            yk0 += base[128 + d0]     * kw[d0 * 3 + tau];
            yk1 += base[128 + d0 + 1] * kw[(d0 + 1) * 3 + tau];
        }
    }
    yq0 = 1.0f / (1.0f + __expf(-yq0));
    yq1 = 1.0f / (1.0f + __expf(-yq1));
    yk0 = 1.0f / (1.0f + __expf(-yk0));
    yk1 = 1.0f / (1.0f + __expf(-yk1));
    float sq = yq0 * yq0 + yq1 * yq1;
    float sk = yk0 * yk0 + yk1 * yk1;
#pragma unroll
    for (int msk = 1; msk <= 32; msk <<= 1) {
        sq += __shfl_xor(sq, msk);
        sk += __shfl_xor(sk, msk);
    }
    float rq = 1.0f / fmaxf(sqrtf(sq), 1e-12f);
    float rk = 1.0f / fmaxf(sqrtf(sk), 1e-12f);
    float k0n = yk0 * rk, k1n = yk1 * rk;
    float a0 = ab[(size_t)m * 256 + d0];
    float a1 = ab[(size_t)m * 256 + d0 + 1];
    float b0 = ab[(size_t)m * 256 + 128 + d0];
    float b1 = ab[(size_t)m * 256 + 128 + d0 + 1];
    float v0 = qkv[(size_t)m * 512 + 256 + d0];
    float v1 = qkv[(size_t)m * 512 + 256 + d0 + 1];
    float* P = pack + ((size_t)b * 512 + (l >> 2)) * 2560 + (l & 3);
    P[d0 * 4]              = k0n;      P[(d0 + 1) * 4]        = k1n;
    P[512 + d0 * 4]        = b0 * k0n; P[512 + (d0 + 1) * 4]  = b1 * k1n;
    P[1024 + d0 * 4]       = a0;       P[1024 + (d0 + 1) * 4] = a1;
    P[1536 + d0 * 4]       = yq0 * rq; P[1536 + (d0 + 1) * 4] = yq1 * rq;
    P[2048 + d0 * 4]       = v0;       P[2048 + (d0 + 1) * 4] = v1;
}

// ---------------------------------------------------------------------------
// Barrier-free delta-rule recurrence, R=2 rows/wave COLUMN-SHARDED, HALF
// sequence per call. Grid 512 = BB*64 one-wave WGs (2/CU).
// R12 lesson: recur1 was L3-BW-bound on stream duplication (128 waves/batch
// x 1536 B/step ~ 10 TB/s). Here 64 waves/batch read the same streams
// (dup halved) and slices halve (pout 537->268 MB).
// Lane holds cols {2l,2l+1} of BOTH rows r0=2g, r0+1 -> S0[2], S1[2]:
// single layout, no iA/pown selects (unlike R11's dual-layout R=2).
// Per step: 2-col dots for both rows -> two interleaved allreduce16 +
// 8 readlane + 6 add -> sk0, sk1 (uniform) -> 12-op update -> 4-op output
// -> packed bf16 store  (~50 VALU).
// TB=4 blocked operands, depth-2 block pipeline, sched_barrier(0) after
// each PREB (R11: pins load-issue, keeps both buffers live).
// ---------------------------------------------------------------------------
__global__ __launch_bounds__(64, 1) void recur2c_kernel(
    const float* __restrict__ pack, const float* __restrict__ sin,
    __hip_bfloat16* __restrict__ pout, float* __restrict__ sout, int blk0)
{
    const int lane = threadIdx.x;
    const int b = blockIdx.x >> 6;
    const int g = blockIdx.x & 63;
    const int r0 = g * 2;
    const int j0 = lane * 2;

    float S0[2], S1[2];
    {
        const float* sp = sin + ((size_t)b * DD + r0) * DD + j0;
        float2 t2 = *(const float2*)sp;
        S0[0] = t2.x; S0[1] = t2.y;
        sp += DD;
        t2 = *(const float2*)sp;
        S1[0] = t2.x; S1[1] = t2.y;
    }

    const float* P = pack + ((size_t)b * 512 + blk0) * 2560;
    __hip_bfloat16* po = pout + ((size_t)g * (BB * LH) + (size_t)b * LH) * DD + j0;

    // block-level double buffers (statically indexed)
    float4 ka4[2][2], ma4[2][2], aa4[2][2];
    float4 qv4[2][2], vv4[2][2];

#define PREB(BF)                                                             \
    do {                                                                     \
        ka4[BF][0] = *(const float4*)(P + j0 * 4);                           \
        ka4[BF][1] = *(const float4*)(P + j0 * 4 + 4);                       \
        ma4[BF][0] = *(const float4*)(P + 512 + j0 * 4);                     \
        ma4[BF][1] = *(const float4*)(P + 512 + j0 * 4 + 4);                 \
        aa4[BF][0] = *(const float4*)(P + 1024 + j0 * 4);                    \
        aa4[BF][1] = *(const float4*)(P + 1024 + j0 * 4 + 4);                \
        qv4[BF][0] = *(const float4*)(P + 1536 + r0 * 4);                    \
        qv4[BF][1] = *(const float4*)(P + 1536 + r0 * 4 + 4);                \
        vv4[BF][0] = *(const float4*)(P + 2048 + r0 * 4);                    \
        vv4[BF][1] = *(const float4*)(P + 2048 + r0 * 4 + 4);                \
        P += 2560;                                                           \
        __builtin_amdgcn_sched_barrier(0);  /* pin load-issue point */       \
    } while (0)

#define STEPQ(BF, CMP)                                                       \
    do {                                                                     \
        float k0 = ka4[BF][0].CMP, k1 = ka4[BF][1].CMP;                      \
        float e0 = S0[0] * k0; e0 = fmaf(S0[1], k1, e0);                     \
        float e1 = S1[0] * k0; e1 = fmaf(S1[1], k1, e1);                     \
        float p0 = allreduce16(e0);                                          \
        float p1 = allreduce16(e1);                                          \
        float sk0 = (rlane(p0, 0) + rlane(p0, 16))                           \
                  + (rlane(p0, 32) + rlane(p0, 48));                         \
        float sk1 = (rlane(p1, 0) + rlane(p1, 16))                           \
                  + (rlane(p1, 32) + rlane(p1, 48));                         \
        float v0 = vv4[BF][0].CMP, v1 = vv4[BF][1].CMP;                      \
        float q0 = qv4[BF][0].CMP, q1 = qv4[BF][1].CMP;                      \
        float a0 = aa4[BF][0].CMP, a1 = aa4[BF][1].CMP;                      \
        float m0 = ma4[BF][0].CMP, m1 = ma4[BF][1].CMP;                      \
        float t00 = fmaf(-a0, sk0, v0); S0[0] = fmaf(m0, t00, a0 * S0[0]);   \
        float t10 = fmaf(-a0, sk1, v1); S1[0] = fmaf(m0, t10, a0 * S1[0]);   \
        float t01 = fmaf(-a1, sk0, v0); S0[1] = fmaf(m1, t01, a1 * S0[1]);   \
        float t11 = fmaf(-a1, sk1, v1); S1[1] = fmaf(m1, t11, a1 * S1[1]);   \
        float po0 = fmaf(q1, S1[0], q0 * S0[0]);                             \
        float po1 = fmaf(q1, S1[1], q0 * S0[1]);                             \
        __hip_bfloat162 h2;                                                  \
        h2.x = __float2bfloat16(po0);                                        \
        h2.y = __float2bfloat16(po1);                                        \
        *(__hip_bfloat162*)po = h2;                                          \
        po += DD;                                                            \
    } while (0)

#define STEP4(BF) \
    do { STEPQ(BF, x); STEPQ(BF, y); STEPQ(BF, z); STEPQ(BF, w); } while (0)

    PREB(0);    // block blk0
    PREB(1);    // block blk0+1
    for (int tb = 0; tb < LH / 4; tb += 2) {
        STEP4(0);
        PREB(0);    // blk+2 (final iters overrun into ws: values unused)
        STEP4(1);
        PREB(1);    // blk+3
    }
#undef PREB
#undef STEPQ
#undef STEP4

    {
        float* sp = sout + ((size_t)b * DD + r0) * DD + j0;
        float2 o2 = {S0[0], S0[1]};
        *(float2*)sp = o2;
        sp += DD;
        float2 o3 = {S1[0], S1[1]};
        *(float2*)sp = o3;
    }
}

// ---------------------------------------------------------------------------
// oc(half) = silu(sum_{g<64} pout[g])  bf16 -> fp32. Writes into the DEAD
// half-band of pack: oc(b,h,tl,d) = ocbase[b*2048*640 + h*1024*640 + tl*128 + d]
// (proven R11; same byte ranges under the blocked pack layout).
// ---------------------------------------------------------------------------
__global__ __launch_bounds__(256) void combine_silu_kernel(
    const ushort* __restrict__ pout, float* __restrict__ ocbase, int h)
{
    const size_t NHALF = (size_t)BB * LH * DD;   // elems per slice
    size_t idx = ((size_t)blockIdx.x * 256 + threadIdx.x) * 4;
    float s0 = 0, s1 = 0, s2 = 0, s3 = 0;
#pragma unroll 8
    for (int gi = 0; gi < 64; ++gi) {
        uint2 u = *(const uint2*)(pout + gi * NHALF + idx);
        s0 += __uint_as_float((u.x & 0xffffu) << 16);
        s1 += __uint_as_float(u.x & 0xffff0000u);
        s2 += __uint_as_float((u.y & 0xffffu) << 16);
        s3 += __uint_as_float(u.y & 0xffff0000u);
    }
    float4 r;
    r.x = s0 / (1.0f + __expf(-s0));
    r.y = s1 / (1.0f + __expf(-s1));
    r.z = s2 / (1.0f + __expf(-s2));
    r.w = s3 / (1.0f + __expf(-s3));
    size_t b = idx >> 17;                // / (LH*DD)
    size_t rem = idx & ((size_t)LH * DD - 1);
    float* dst = ocbase + b * (2048ull * 640) + (size_t)h * (1024ull * 640) + rem;
    *(float4*)dst = r;
}

// ---------------------------------------------------------------------------
// d_out = y * rsqrt(mean(y^2)+1e-6) * rms_w + residual. One wave per (b,l).
// ---------------------------------------------------------------------------
__global__ __launch_bounds__(256) void rms_res_kernel(
    const float* __restrict__ y, const float* __restrict__ res,
    const float* __restrict__ rmsw, float* __restrict__ out)
{
    const int tid = threadIdx.x;
    const int lane = tid & 63;
    const int wid = tid >> 6;
    const int m = blockIdx.x * 4 + wid;
    const int d0 = lane * 2;
    size_t o = (size_t)m * DD + d0;
    float2 yv = *(const float2*)(y + o);
    float ss = yv.x * yv.x + yv.y * yv.y;
#pragma unroll
    for (int msk = 1; msk <= 32; msk <<= 1) ss += __shfl_xor(ss, msk);
    float r = rsqrtf(ss * (1.0f / 128.0f) + 1e-6f);
    float2 rv = *(const float2*)(res + o);
    out[o]     = yv.x * r * rmsw[d0]     + rv.x;
    out[o + 1] = yv.y * r * rmsw[d0 + 1] + rv.y;
}

// ---------------------------------------------------------------------------
// Workspace (176,160,768 B total — the R7..R12-proven footprint):
//   [0, 41.9MB)   pack2 blocked [B,512,2560] fp32. After each half's
//                 recurrence that half's band is dead -> combine -> oc.
//   [41.9MB, +134.2MB) poreg:
//      phase 1:  qkv [M,512] + abv [M,256]
//      phase 2:  pout bf16, 64 slices x [B,LH,D]  (reused for both halves)
//      phase 3:  res [M,128] + yb [M,128]
// Mid-sequence state lives in sfin (inside d_out): written h0, read h1.
// ---------------------------------------------------------------------------
extern "C" void kernel_launch(void* const* d_in, const int* in_sizes, int n_in,
                              void* d_out, int out_size, void* d_ws, size_t ws_size,
                              hipStream_t stream)
{
    const float* x      = (const float*)d_in[0];
    const float* state  = (const float*)d_in[1];
    const float* W_in   = (const float*)d_in[2];
    const float* W_gate = (const float*)d_in[3];
    const float* W_out  = (const float*)d_in[4];
    const float* W_res  = (const float*)d_in[5];
    const float* qcw    = (const float*)d_in[6];
    const float* qcb    = (const float*)d_in[7];
    const float* kcw    = (const float*)d_in[8];
    const float* kcb    = (const float*)d_in[9];
    const float* rmsw   = (const float*)d_in[10];
    float* out  = (float*)d_out;
    float* sfin = out + (size_t)BB * LL * DD;

    const size_t M = (size_t)BB * LL;            // 16384
    char* base = (char*)d_ws;
    const size_t PACK_BYTES = M * 640 * 4;       // 41.9 MB
    float* pack = (float*)base;
    char*  poreg = base + PACK_BYTES;
    float* qkv = (float*)poreg;                              // phase 1
    float* abv = (float*)(poreg + M * 512 * 4);              // phase 1
    __hip_bfloat16* po = (__hip_bfloat16*)poreg;             // phase 2
    float* res = (float*)poreg;                              // phase 3 (over po)
    float* yb  = (float*)(poreg + M * DD * 4);               // phase 3

    const long ld128 = 128, ld512 = 512;
    dim3 blk(256);
    // qkv = x @ W_in^T  [M,512]
    gemm_kernel<<<dim3(M / 32, 8), blk, 0, stream>>>(
        x, ld128, 2048 * ld128, 1024 * ld128, W_in, qkv, 512, 0);
    // alpha/beta = sigmoid(gate @ W_gate^T) [M,256]
    gemm_kernel<<<dim3(M / 32, 4), blk, 0, stream>>>(
        qkv + 384, ld512, 2048 * ld512, 1024 * ld512, W_gate, abv, 256, 1);
    // conv + sigmoid + l2norm + blocked pack stream [k|m|alpha|q|v] x TB=4
    convnorm_kernel<<<dim3(M / 4), blk, 0, stream>>>(qkv, qcw, qcb, kcw, kcb, abv, pack);
    // recurrence half 0: state -> sfin(mid), partials -> po
    recur2c_kernel<<<dim3(BB * 64), dim3(64), 0, stream>>>(pack, state, po, sfin, 0);
    // combine h0 -> oc half 0 (into pack's dead tb<256 bands)
    combine_silu_kernel<<<dim3((BB * LH * DD) / 1024), blk, 0, stream>>>(
        (const ushort*)po, pack, 0);
    // recurrence half 1: sfin(mid) -> sfin(final), partials -> po (reused)
    recur2c_kernel<<<dim3(BB * 64), dim3(64), 0, stream>>>(pack, sfin, po, sfin, 256);
    // combine h1 -> oc half 1
    combine_silu_kernel<<<dim3((BB * LH * DD) / 1024), blk, 0, stream>>>(
        (const ushort*)po, pack, 1);
    // residual = x @ W_res^T  (po region dead after combine h1)
    gemm_kernel<<<dim3(M / 32, 2), blk, 0, stream>>>(
        x, ld128, 2048 * ld128, 1024 * ld128, W_res, res, 128, 0);
    // y = oc @ W_out^T   (oc scattered in pack: sB=2048*640, sH=1024*640)
    gemm_kernel<<<dim3(M / 32, 2), blk, 0, stream>>>(
        pack, ld128, 2048 * 640, 1024 * 640, W_out, yb, 128, 0);
    // RMS + residual -> d_out
    rms_res_kernel<<<dim3(M / 4), blk, 0, stream>>>(yb, res, rmsw, out);
}